// Round 3
// baseline (3575.187 us; speedup 1.0000x reference)
//
#include <hip/hip_runtime.h>
#include <stdint.h>

typedef unsigned short u16;
typedef unsigned int   u32;

typedef __bf16 bf16x8 __attribute__((ext_vector_type(8)));
typedef float  f32x4  __attribute__((ext_vector_type(4)));

// Sizes: B=256, T=64, H=256, M2=512, gates=1024
// ws layout (bytes):
//   WattB  bf16 B-frag [nt<16][ks<16][lane<64][i<8] : off 0,       sz 262144
//   WencB  bf16 B-frag [nt<16][ks<16][lane<64][i<8] : off 262144,  sz 262144
//   WhhB   bf16 B-frag [j][nt<64][ks<8][lane][i]    : off 524288,  sz 1048576
//   beff   f32 [256]                                : off 1572864
//   gbias  f32 [2][1024]                            : off 1573888
//   fcE    f32 [515]                                : off 1582080

__device__ __forceinline__ float bf2f(u16 v){ return __uint_as_float(((u32)v) << 16); }
__device__ __forceinline__ u16 f2bf(float f){
  u32 u = __float_as_uint(f);
  u += 0x7fffu + ((u >> 16) & 1u);
  return (u16)(u >> 16);
}
__device__ __forceinline__ u32 pk2(float a, float b){
  return (u32)f2bf(a) | (((u32)f2bf(b)) << 16);
}
__device__ __forceinline__ float wave_sum(float v){
  #pragma unroll
  for (int o = 32; o > 0; o >>= 1) v += __shfl_xor(v, o, 64);
  return v;
}
__device__ __forceinline__ float tanh_fast(float x){
  float e = __builtin_amdgcn_exp2f(x * 2.88539008178f); // 2*log2(e)
  return 1.0f - 2.0f * __builtin_amdgcn_rcpf(1.0f + e);
}
__device__ __forceinline__ float sigm(float x){
  float e = __builtin_amdgcn_exp2f(-x * 1.44269504089f);
  return __builtin_amdgcn_rcpf(1.0f + e);
}
__device__ __forceinline__ f32x4 mfma16(bf16x8 a, bf16x8 b, f32x4 c){
  return __builtin_amdgcn_mfma_f32_16x16x32_bf16(a, b, c, 0, 0, 0);
}
// B-fragment index for 16x16x32: element (k, n), KS = K/32 tiles along K.
// lane = ((k>>3)&3)*16 + (n&15), i = k&7, tile (nt=n>>4, ks=k>>5)
__device__ __forceinline__ size_t bfrag_idx(int n, int k, int KS){
  return ((size_t)((n >> 4) * KS + (k >> 5)) * 64 + ((k >> 3) & 3) * 16 + (n & 15)) * 8 + (k & 7);
}

// ---------------- prep kernels ----------------

// Weff = attn_w2 @ attn_w1 (256 x 1024); cols 0..511 -> WattB (B-frag, K=512),
// cols 512..1023 -> WencB (B-frag, K=512 over enc dim). beff = w2@b1 + b2.
__global__ __launch_bounds__(256) void prep_attn(
    const float* __restrict__ w1, const float* __restrict__ b1,
    const float* __restrict__ w2, const float* __restrict__ b2,
    u16* __restrict__ WattB, u16* __restrict__ WencB, float* __restrict__ beff)
{
  const int h = blockIdx.x, tid = threadIdx.x;
  __shared__ float w2row[256];
  __shared__ float red[256];
  w2row[tid] = w2[h * 256 + tid];
  __syncthreads();
  float acc0 = 0.f, acc1 = 0.f, acc2 = 0.f, acc3 = 0.f;
  for (int m = 0; m < 256; ++m){
    const float wm = w2row[m];
    const float* r = w1 + m * 1024 + tid;
    acc0 += wm * r[0];
    acc1 += wm * r[256];
    acc2 += wm * r[512];
    acc3 += wm * r[768];
  }
  WattB[bfrag_idx(h, tid,       16)] = f2bf(acc0);
  WattB[bfrag_idx(h, tid + 256, 16)] = f2bf(acc1);
  WencB[bfrag_idx(h, tid,       16)] = f2bf(acc2);
  WencB[bfrag_idx(h, tid + 256, 16)] = f2bf(acc3);
  red[tid] = w2row[tid] * b1[tid];
  __syncthreads();
  for (int s = 128; s > 0; s >>= 1){
    if (tid < s) red[tid] += red[tid + s];
    __syncthreads();
  }
  if (tid == 0) beff[h] = red[0] + b2[h];
}

// Pack w_hh_{f,b} into B-frag layout (K=256, KS=8); gbias[j][n] = b_ih + b_hh
__global__ __launch_bounds__(256) void prep_whh(
    const float* __restrict__ whhf, const float* __restrict__ whhb,
    const float* __restrict__ bihf, const float* __restrict__ bhhf,
    const float* __restrict__ bihb, const float* __restrict__ bhhb,
    u16* __restrict__ WhhB, float* __restrict__ gbias)
{
  const int e = blockIdx.x * 256 + threadIdx.x;  // < 524288
  const int j = e >> 18;
  const int r = e & 262143;
  const int n = r >> 8;
  const int k = r & 255;
  const float* w = j ? whhb : whhf;
  WhhB[(size_t)j * 262144 + bfrag_idx(n, k, 8)] = f2bf(w[n * 256 + k]);
  if (e < 2048){
    const int jj = e >> 10, nn = e & 1023;
    gbias[e] = jj ? (bihb[nn] + bhhb[nn]) : (bihf[nn] + bhhf[nn]);
  }
}

__global__ __launch_bounds__(256) void prep_fc(
    const float* __restrict__ fcw1, const float* __restrict__ fcb1,
    const float* __restrict__ fcw2, const float* __restrict__ fcb2,
    float* __restrict__ fcE)
{
  const int tid = threadIdx.x;
  __shared__ float w2s[256];
  __shared__ float red[256];
  w2s[tid] = fcw2[tid];
  __syncthreads();
  for (int m = tid; m < 514; m += 256){
    float a = 0.f;
    for (int hh = 0; hh < 256; ++hh) a += w2s[hh] * fcw1[hh * 514 + m];
    fcE[m] = a;
  }
  red[tid] = w2s[tid] * fcb1[tid];
  __syncthreads();
  for (int s = 128; s > 0; s >>= 1){
    if (tid < s) red[tid] += red[tid + s];
    __syncthreads();
  }
  if (tid == 0) fcE[514] = red[0] + fcb2[0];
}

// ---------------- main kernel: 1024 threads (16 waves) per batch element ----------------
__global__ __launch_bounds__(1024, 4) void decoder_main(
    const float* __restrict__ enc,   const float* __restrict__ yhist,
    const float* __restrict__ speed, const float* __restrict__ h0,
    const float* __restrict__ c0,    const float* __restrict__ aw3,
    const float* __restrict__ wihf,  const float* __restrict__ wihb,
    const float* __restrict__ fcfw,  const float* __restrict__ fcfb,
    const u16* __restrict__ WattB,   const u16* __restrict__ WencB,
    const u16* __restrict__ WhhB,    const float* __restrict__ beff,
    const float* __restrict__ gbias, const float* __restrict__ fcE,
    float* __restrict__ out)
{
  const int b = blockIdx.x, tid = threadIdx.x;
  const int lane = tid & 63, wv = tid >> 6;   // wv < 16
  const int q = lane >> 4, col = lane & 15;

  __shared__ float hcin[2][512];            // fp32 state: [j][k<256]=h, [256..512)=c
  __shared__ alignas(16) u16 hcB[2][512];   // bf16 mirror (MFMA A-side)
  __shared__ alignas(16) u16 encT[64 * 256];   // enc attention term (bf16)
  __shared__ alignas(16) u16 encLDS[64 * 512]; // raw enc (bf16) for P3
  __shared__ float hcp[2][256];
  __shared__ float ctxp[2][512];
  __shared__ float ctx[512];
  __shared__ float attw[64];
  __shared__ float attw_acc[64];
  __shared__ float scores[64];
  __shared__ float red[16];
  __shared__ float preS[2][1024];           // raw gate dots from MFMA

  // ---- init state ----
  if (tid < 512){
    const int j = tid >> 8, p = tid & 255;
    const float hv = h0[j * 65536 + b * 256 + p];
    const float cv = c0[j * 65536 + b * 256 + p];
    hcin[j][p]       = hv;
    hcin[j][256 + p] = cv;
    hcB[j][p]        = f2bf(hv);
    hcB[j][256 + p]  = f2bf(cv);
  }
  if (tid < 64) attw_acc[tid] = 0.f;

  const float* encB = enc + (size_t)b * 32768;

  // ---- prologue: encT[s][h] = enc[b,s,:].WencB + beff (MFMA GEMM, M=64,K=512,N=256)
  // wave wv: mt = wv>>2 (s-tile), g = wv&3 (nt group of 4). g==0 waves also stash encLDS.
  {
    const int mt = wv >> 2, g = wv & 3;
    const int s = mt * 16 + col;
    f32x4 acc[4];
    #pragma unroll
    for (int tt = 0; tt < 4; ++tt) acc[tt] = (f32x4){0.f, 0.f, 0.f, 0.f};
    for (int ks = 0; ks < 16; ++ks){
      const float* ap = encB + s * 512 + ks * 32 + q * 8;
      const float4 e0 = *(const float4*)ap;
      const float4 e1 = *(const float4*)(ap + 4);
      uint4 af;
      af.x = pk2(e0.x, e0.y); af.y = pk2(e0.z, e0.w);
      af.z = pk2(e1.x, e1.y); af.w = pk2(e1.z, e1.w);
      if (g == 0) *(uint4*)&encLDS[s * 512 + ks * 32 + q * 8] = af;
      const bf16x8 a = __builtin_bit_cast(bf16x8, af);
      #pragma unroll
      for (int tt = 0; tt < 4; ++tt){
        const int nt = g * 4 + tt;
        const uint4 bw = *(const uint4*)(WencB + (((nt * 16 + ks) * 64 + lane) << 3));
        acc[tt] = mfma16(a, __builtin_bit_cast(bf16x8, bw), acc[tt]);
      }
    }
    #pragma unroll
    for (int tt = 0; tt < 4; ++tt){
      const int nt = g * 4 + tt;
      const float bv = beff[nt * 16 + col];
      #pragma unroll
      for (int r = 0; r < 4; ++r)
        encT[(mt * 16 + q * 4 + r) * 256 + nt * 16 + col] = f2bf(acc[tt][r] + bv);
    }
  }

  // ---- per-thread constants ----
  const int m3 = tid & 511, sh2 = tid >> 9;
  const int jj = (tid >> 8) & 1, pp = tid & 255;   // update-phase ids (valid for tid<512)
  const float* wihJ = jj ? wihb : wihf;
  const float wv_i = wihJ[pp], wv_f = wihJ[pp + 256], wv_g = wihJ[pp + 512], wv_o = wihJ[pp + 768];
  const float gb_i = gbias[jj * 1024 + pp],       gb_f = gbias[jj * 1024 + pp + 256];
  const float gb_g = gbias[jj * 1024 + pp + 512], gb_o = gbias[jj * 1024 + pp + 768];
  const float fe  = fcE[m3];
  const float feY = fcE[512], feS = fcE[513], feB = fcE[514];
  const float w3q0 = aw3[lane], w3q1 = aw3[lane + 64],
              w3q2 = aw3[lane + 128], w3q3 = aw3[lane + 192];

  // ---- 64 sequential decode steps ----
  for (int t = 0; t < 64; ++t){
    __syncthreads();  // S0: state (hcB/hcin), encT/encLDS (t=0), preS consumed

    // P1: hcp[v][h] = [h_v,c_v] . Weff  (MFMA; A rows alternate v=lane&1; wave wv: nt=wv)
    {
      f32x4 acc1 = (f32x4){0.f, 0.f, 0.f, 0.f};
      #pragma unroll 4
      for (int ks = 0; ks < 16; ++ks){
        const uint4 av = *(const uint4*)&hcB[lane & 1][ks * 32 + q * 8];
        const uint4 bw = *(const uint4*)(WattB + (((wv * 16 + ks) * 64 + lane) << 3));
        acc1 = mfma16(__builtin_bit_cast(bf16x8, av), __builtin_bit_cast(bf16x8, bw), acc1);
      }
      if (lane < 16){
        hcp[0][wv * 16 + lane] = acc1[0];   // D row 0 = v0
        hcp[1][wv * 16 + lane] = acc1[1];   // D row 1 = v1
      }
    }

    // P4: gate dots g = h_j . Whh_j (MFMA, all A rows = h_j; wave: j=wv>>3, 8 nt tiles)
    {
      const int j = wv >> 3, ntb = (wv & 7) * 8;
      bf16x8 a4[8];
      #pragma unroll
      for (int ks = 0; ks < 8; ++ks)
        a4[ks] = __builtin_bit_cast(bf16x8, *(const uint4*)&hcB[j][ks * 32 + q * 8]);
      f32x4 acc[8];
      #pragma unroll
      for (int tt = 0; tt < 8; ++tt) acc[tt] = (f32x4){0.f, 0.f, 0.f, 0.f};
      const u16* wb = WhhB + j * 262144;
      #pragma unroll
      for (int tt = 0; tt < 8; ++tt){
        #pragma unroll
        for (int ks = 0; ks < 8; ++ks){
          const uint4 bw = *(const uint4*)(wb + ((((ntb + tt) * 8 + ks) * 64 + lane) << 3));
          acc[tt] = mfma16(a4[ks], __builtin_bit_cast(bf16x8, bw), acc[tt]);
        }
      }
      if (lane < 16){
        #pragma unroll
        for (int tt = 0; tt < 8; ++tt)
          preS[j][(ntb + tt) * 16 + lane] = acc[tt][0];  // all D rows equal
      }
    }
    __syncthreads();  // S1: hcp, preS ready

    // P2: scores[s] = sum_h w3[h]*tanh(encT[s][h] + hcp[s&1][h]); wave wv: s = wv*4+r
    {
      float hqA[4], hqB[4];
      #pragma unroll
      for (int qq = 0; qq < 4; ++qq){
        hqA[qq] = hcp[0][lane + 64 * qq];
        hqB[qq] = hcp[1][lane + 64 * qq];
      }
      #pragma unroll
      for (int r = 0; r < 4; ++r){
        const int s = wv * 4 + r;
        const float h0v = (r & 1) ? hqB[0] : hqA[0];
        const float h1v = (r & 1) ? hqB[1] : hqA[1];
        const float h2v = (r & 1) ? hqB[2] : hqA[2];
        const float h3v = (r & 1) ? hqB[3] : hqA[3];
        float psum = w3q0 * tanh_fast(bf2f(encT[s * 256 + lane])       + h0v)
                   + w3q1 * tanh_fast(bf2f(encT[s * 256 + lane + 64])  + h1v)
                   + w3q2 * tanh_fast(bf2f(encT[s * 256 + lane + 128]) + h2v)
                   + w3q3 * tanh_fast(bf2f(encT[s * 256 + lane + 192]) + h3v);
        psum = wave_sum(psum);
        if (lane == 0) scores[s] = psum;
      }
    }
    __syncthreads();  // S2: scores ready

    // softmax (wave 0)
    if (tid < 64){
      const float v = scores[tid];
      float mx = v;
      #pragma unroll
      for (int o = 32; o > 0; o >>= 1) mx = fmaxf(mx, __shfl_xor(mx, o, 64));
      const float e = __builtin_amdgcn_exp2f((v - mx) * 1.44269504089f);
      float sm = e;
      #pragma unroll
      for (int o = 32; o > 0; o >>= 1) sm += __shfl_xor(sm, o, 64);
      const float a = e / sm;
      attw[tid] = a;
      attw_acc[tid] += a;
    }
    __syncthreads();  // S3: attw ready

    // P3: context partials from LDS bf16 enc; thread = (m3, sh2), 32 s each
    {
      float ca = 0.f;
      #pragma unroll 8
      for (int si = 0; si < 32; ++si){
        const int s = sh2 * 32 + si;
        ca += attw[s] * bf2f(encLDS[s * 512 + m3]);
      }
      ctxp[sh2][m3] = ca;
    }
    __syncthreads();  // S4: ctxp ready

    if (tid < 512){
      const float c = ctxp[0][tid] + ctxp[1][tid];
      ctx[tid] = c;
      float yp = c * fe;
      yp = wave_sum(yp);
      if (lane == 0) red[wv] = yp;
    }
    __syncthreads();  // S5: red ready

    // update: LSTM cell (tid<512); preS holds raw gate dots
    if (tid < 512){
      const float yt = yhist[b * 64 + t];
      const float st = speed[b * 64 + t];
      const float ytil = (red[0] + red[1] + red[2] + red[3] +
                          red[4] + red[5] + red[6] + red[7]) +
                         yt * feY + st * feS + feB;
      const float pi = preS[jj][pp]       + ytil * wv_i + gb_i;
      const float pf = preS[jj][pp + 256] + ytil * wv_f + gb_f;
      const float pg = preS[jj][pp + 512] + ytil * wv_g + gb_g;
      const float po = preS[jj][pp + 768] + ytil * wv_o + gb_o;
      const float cold = hcin[jj][256 + pp];
      const float cnew = sigm(pf) * cold + sigm(pi) * tanh_fast(pg);
      const float hnew = sigm(po) * tanh_fast(cnew);
      hcin[jj][256 + pp] = cnew;
      hcin[jj][pp]       = hnew;
      hcB[jj][pp]        = f2bf(hnew);
      hcB[jj][256 + pp]  = f2bf(cnew);
    }
  }

  __syncthreads();

  // ---- outputs ----
  if (tid < 64) out[b * 64 + tid] = attw_acc[tid] * 0.015625f;  // /64

  if (tid < 256){
    float part = hcin[0][tid]     * fcfw[tid]
               + ctx[tid]         * fcfw[256 + tid]
               + ctx[256 + tid]   * fcfw[512 + tid];
    part = wave_sum(part);
    if (lane == 0) red[wv] = part;
  }
  __syncthreads();
  if (tid == 0) out[16384 + b] = red[0] + red[1] + red[2] + red[3] + fcfb[0];
}

// ---------------- launch ----------------
extern "C" void kernel_launch(void* const* d_in, const int* in_sizes, int n_in,
                              void* d_out, int out_size, void* d_ws, size_t ws_size,
                              hipStream_t stream)
{
  const float* enc  = (const float*)d_in[0];
  const float* yh   = (const float*)d_in[1];
  const float* sp   = (const float*)d_in[2];
  const float* h0   = (const float*)d_in[3];
  const float* c0   = (const float*)d_in[4];
  const float* w1   = (const float*)d_in[5];
  const float* b1   = (const float*)d_in[6];
  const float* w2   = (const float*)d_in[7];
  const float* b2   = (const float*)d_in[8];
  const float* w3   = (const float*)d_in[9];
  const float* wihf = (const float*)d_in[11];
  const float* whhf = (const float*)d_in[12];
  const float* bihf = (const float*)d_in[13];
  const float* bhhf = (const float*)d_in[14];
  const float* wihb = (const float*)d_in[15];
  const float* whhb = (const float*)d_in[16];
  const float* bihb = (const float*)d_in[17];
  const float* bhhb = (const float*)d_in[18];
  const float* fcw1 = (const float*)d_in[19];
  const float* fcb1 = (const float*)d_in[20];
  const float* fcw2 = (const float*)d_in[21];
  const float* fcb2 = (const float*)d_in[22];
  const float* fcfw = (const float*)d_in[23];
  const float* fcfb = (const float*)d_in[24];

  char* ws = (char*)d_ws;
  u16*   WattB = (u16*)(ws);
  u16*   WencB = (u16*)(ws + 262144);
  u16*   WhhB  = (u16*)(ws + 524288);
  float* beff  = (float*)(ws + 1572864);
  float* gbias = (float*)(ws + 1573888);
  float* fcE   = (float*)(ws + 1582080);
  float* out   = (float*)d_out;

  prep_attn<<<dim3(256),  dim3(256), 0, stream>>>(w1, b1, w2, b2, WattB, WencB, beff);
  prep_whh <<<dim3(2048), dim3(256), 0, stream>>>(whhf, whhb, bihf, bhhf, bihb, bhhb, WhhB, gbias);
  prep_fc  <<<dim3(1),    dim3(256), 0, stream>>>(fcw1, fcb1, fcw2, fcb2, fcE);
  decoder_main<<<dim3(256), dim3(1024), 0, stream>>>(
      enc, yh, sp, h0, c0, w3, wihf, wihb, fcfw, fcfb,
      WattB, WencB, WhhB, beff, gbias, fcE, out);
}

// Round 4
// 1509.795 us; speedup vs baseline: 2.3680x; 2.3680x over previous
//
#include <hip/hip_runtime.h>
#include <stdint.h>

typedef unsigned short u16;
typedef unsigned int   u32;

typedef __bf16 bf16x8 __attribute__((ext_vector_type(8)));
typedef float  f32x4  __attribute__((ext_vector_type(4)));

// Sizes: B=256, T=64, H=256, M2=512, gates=1024
// ws layout (bytes):
//   WattB  bf16 B-frag [nt<16][ks<16][lane<64][i<8] : off 0,       sz 262144
//   WencB  bf16 B-frag [nt<16][ks<16][lane<64][i<8] : off 262144,  sz 262144
//   WhhB   bf16 B-frag [j][nt<64][ks<8][lane][i]    : off 524288,  sz 1048576
//   beff   f32 [256]                                : off 1572864
//   gbias  f32 [2][1024]                            : off 1573888
//   fcE    f32 [515]                                : off 1582080

__device__ __forceinline__ float bf2f(u16 v){ return __uint_as_float(((u32)v) << 16); }
__device__ __forceinline__ u16 f2bf(float f){
  u32 u = __float_as_uint(f);
  u += 0x7fffu + ((u >> 16) & 1u);
  return (u16)(u >> 16);
}
__device__ __forceinline__ u32 pk2(float a, float b){
  return (u32)f2bf(a) | (((u32)f2bf(b)) << 16);
}
__device__ __forceinline__ float wave_sum(float v){
  #pragma unroll
  for (int o = 32; o > 0; o >>= 1) v += __shfl_xor(v, o, 64);
  return v;
}
__device__ __forceinline__ float tanh_fast(float x){
  float e = __builtin_amdgcn_exp2f(x * 2.88539008178f); // 2*log2(e)
  return 1.0f - 2.0f * __builtin_amdgcn_rcpf(1.0f + e);
}
__device__ __forceinline__ float sigm(float x){
  float e = __builtin_amdgcn_exp2f(-x * 1.44269504089f);
  return __builtin_amdgcn_rcpf(1.0f + e);
}
__device__ __forceinline__ f32x4 mfma16(bf16x8 a, bf16x8 b, f32x4 c){
  return __builtin_amdgcn_mfma_f32_16x16x32_bf16(a, b, c, 0, 0, 0);
}
// B-fragment index for 16x16x32: element (k, n), KS = K/32 tiles along K.
// lane = ((k>>3)&3)*16 + (n&15), i = k&7, tile (nt=n>>4, ks=k>>5)
__device__ __forceinline__ size_t bfrag_idx(int n, int k, int KS){
  return ((size_t)((n >> 4) * KS + (k >> 5)) * 64 + ((k >> 3) & 3) * 16 + (n & 15)) * 8 + (k & 7);
}

// ---------------- prep kernels (unchanged, verified) ----------------

__global__ __launch_bounds__(256) void prep_attn(
    const float* __restrict__ w1, const float* __restrict__ b1,
    const float* __restrict__ w2, const float* __restrict__ b2,
    u16* __restrict__ WattB, u16* __restrict__ WencB, float* __restrict__ beff)
{
  const int h = blockIdx.x, tid = threadIdx.x;
  __shared__ float w2row[256];
  __shared__ float red[256];
  w2row[tid] = w2[h * 256 + tid];
  __syncthreads();
  float acc0 = 0.f, acc1 = 0.f, acc2 = 0.f, acc3 = 0.f;
  for (int m = 0; m < 256; ++m){
    const float wm = w2row[m];
    const float* r = w1 + m * 1024 + tid;
    acc0 += wm * r[0];
    acc1 += wm * r[256];
    acc2 += wm * r[512];
    acc3 += wm * r[768];
  }
  WattB[bfrag_idx(h, tid,       16)] = f2bf(acc0);
  WattB[bfrag_idx(h, tid + 256, 16)] = f2bf(acc1);
  WencB[bfrag_idx(h, tid,       16)] = f2bf(acc2);
  WencB[bfrag_idx(h, tid + 256, 16)] = f2bf(acc3);
  red[tid] = w2row[tid] * b1[tid];
  __syncthreads();
  for (int s = 128; s > 0; s >>= 1){
    if (tid < s) red[tid] += red[tid + s];
    __syncthreads();
  }
  if (tid == 0) beff[h] = red[0] + b2[h];
}

__global__ __launch_bounds__(256) void prep_whh(
    const float* __restrict__ whhf, const float* __restrict__ whhb,
    const float* __restrict__ bihf, const float* __restrict__ bhhf,
    const float* __restrict__ bihb, const float* __restrict__ bhhb,
    u16* __restrict__ WhhB, float* __restrict__ gbias)
{
  const int e = blockIdx.x * 256 + threadIdx.x;  // < 524288
  const int j = e >> 18;
  const int r = e & 262143;
  const int n = r >> 8;
  const int k = r & 255;
  const float* w = j ? whhb : whhf;
  WhhB[(size_t)j * 262144 + bfrag_idx(n, k, 8)] = f2bf(w[n * 256 + k]);
  if (e < 2048){
    const int jj = e >> 10, nn = e & 1023;
    gbias[e] = jj ? (bihb[nn] + bhhb[nn]) : (bihf[nn] + bhhf[nn]);
  }
}

__global__ __launch_bounds__(256) void prep_fc(
    const float* __restrict__ fcw1, const float* __restrict__ fcb1,
    const float* __restrict__ fcw2, const float* __restrict__ fcb2,
    float* __restrict__ fcE)
{
  const int tid = threadIdx.x;
  __shared__ float w2s[256];
  __shared__ float red[256];
  w2s[tid] = fcw2[tid];
  __syncthreads();
  for (int m = tid; m < 514; m += 256){
    float a = 0.f;
    for (int hh = 0; hh < 256; ++hh) a += w2s[hh] * fcw1[hh * 514 + m];
    fcE[m] = a;
  }
  red[tid] = w2s[tid] * fcb1[tid];
  __syncthreads();
  for (int s = 128; s > 0; s >>= 1){
    if (tid < s) red[tid] += red[tid + s];
    __syncthreads();
  }
  if (tid == 0) fcE[514] = red[0] + fcb2[0];
}

// ---------------- main kernel: 1024 threads (16 waves) per batch element ----------------
__global__ __launch_bounds__(1024, 4) void decoder_main(
    const float* __restrict__ enc,   const float* __restrict__ yhist,
    const float* __restrict__ speed, const float* __restrict__ h0,
    const float* __restrict__ c0,    const float* __restrict__ aw3,
    const float* __restrict__ wihf,  const float* __restrict__ wihb,
    const float* __restrict__ fcfw,  const float* __restrict__ fcfb,
    const u16* __restrict__ WattB,   const u16* __restrict__ WencB,
    const u16* __restrict__ WhhB,    const float* __restrict__ beff,
    const float* __restrict__ gbias, const float* __restrict__ fcE,
    float* __restrict__ out)
{
  const int b = blockIdx.x, tid = threadIdx.x;
  const int lane = tid & 63, wv = tid >> 6;   // wv < 16
  const int q = lane >> 4, col = lane & 15;

  __shared__ float hcin[2][512];            // fp32 state: [j][k<256]=h, [256..512)=c
  __shared__ alignas(16) u16 hcB[2][512];   // bf16 mirror (MFMA A-side)
  __shared__ alignas(16) u16 encT[64 * 256];   // enc attention term (bf16)
  __shared__ alignas(16) u16 encLDS[64 * 512]; // raw enc (bf16) for P3
  __shared__ float hcp[2][256];
  __shared__ float ctxp[2][512];
  __shared__ float ctx[512];
  __shared__ float attw[64];
  __shared__ float attw_acc[64];
  __shared__ float scores[64];
  __shared__ float red[16];
  __shared__ float preS[2][1024];           // raw gate dots from MFMA
  __shared__ float yS[64], sS[64];

  // ---- init state ----
  if (tid < 512){
    const int j = tid >> 8, p = tid & 255;
    const float hv = h0[j * 65536 + b * 256 + p];
    const float cv = c0[j * 65536 + b * 256 + p];
    hcin[j][p]       = hv;
    hcin[j][256 + p] = cv;
    hcB[j][p]        = f2bf(hv);
    hcB[j][256 + p]  = f2bf(cv);
  }
  if (tid < 64){
    attw_acc[tid] = 0.f;
    yS[tid] = yhist[b * 64 + tid];
    sS[tid] = speed[b * 64 + tid];
  }

  const float* encB = enc + (size_t)b * 32768;

  // ---- prologue: encT[s][h] = enc[b,s,:].WencB + beff (MFMA GEMM, M=64,K=512,N=256)
  // wave wv: mt = wv>>2 (s-tile), g = wv&3 (nt group of 4). g==0 waves also stash encLDS.
  {
    const int mt = wv >> 2, g = wv & 3;
    const int s = mt * 16 + col;
    f32x4 acc[4];
    #pragma unroll
    for (int tt = 0; tt < 4; ++tt) acc[tt] = (f32x4){0.f, 0.f, 0.f, 0.f};
    #pragma unroll 1
    for (int ks = 0; ks < 16; ++ks){
      const float* ap = encB + s * 512 + ks * 32 + q * 8;
      const float4 e0 = *(const float4*)ap;
      const float4 e1 = *(const float4*)(ap + 4);
      uint4 af;
      af.x = pk2(e0.x, e0.y); af.y = pk2(e0.z, e0.w);
      af.z = pk2(e1.x, e1.y); af.w = pk2(e1.z, e1.w);
      if (g == 0) *(uint4*)&encLDS[s * 512 + ks * 32 + q * 8] = af;
      const bf16x8 a = __builtin_bit_cast(bf16x8, af);
      #pragma unroll
      for (int tt = 0; tt < 4; ++tt){
        const int nt = g * 4 + tt;
        const uint4 bw = *(const uint4*)(WencB + (((nt * 16 + ks) * 64 + lane) << 3));
        acc[tt] = mfma16(a, __builtin_bit_cast(bf16x8, bw), acc[tt]);
      }
    }
    #pragma unroll
    for (int tt = 0; tt < 4; ++tt){
      const int nt = g * 4 + tt;
      const float bv = beff[nt * 16 + col];
      #pragma unroll
      for (int r = 0; r < 4; ++r)
        encT[(mt * 16 + q * 4 + r) * 256 + nt * 16 + col] = f2bf(acc[tt][r] + bv);
    }
  }

  // ---- per-thread constants ----
  const int m3 = tid & 511, sh2 = tid >> 9;
  const int jj = (tid >> 8) & 1, pp = tid & 255;   // update-phase ids (valid for tid<512)
  const float* wihJ = jj ? wihb : wihf;
  const float wv_i = wihJ[pp], wv_f = wihJ[pp + 256], wv_g = wihJ[pp + 512], wv_o = wihJ[pp + 768];
  const float gb_i = gbias[jj * 1024 + pp],       gb_f = gbias[jj * 1024 + pp + 256];
  const float gb_g = gbias[jj * 1024 + pp + 512], gb_o = gbias[jj * 1024 + pp + 768];
  const float fe  = fcE[m3];
  const float feY = fcE[512], feS = fcE[513], feB = fcE[514];
  const float w3q0 = aw3[lane], w3q1 = aw3[lane + 64],
              w3q2 = aw3[lane + 128], w3q3 = aw3[lane + 192];

  // ---- 64 sequential decode steps ----
  #pragma unroll 1
  for (int t = 0; t < 64; ++t){
    __syncthreads();  // S0: state (hcB/hcin), encT/encLDS (t=0), preS consumed

    // P1: hcp[v][h] = [h_v,c_v] . Weff  (MFMA; A rows alternate v=lane&1; wave wv: nt=wv)
    {
      f32x4 acc1 = (f32x4){0.f, 0.f, 0.f, 0.f};
      #pragma unroll
      for (int ks = 0; ks < 16; ++ks){
        const uint4 av = *(const uint4*)&hcB[lane & 1][ks * 32 + q * 8];
        const uint4 bw = *(const uint4*)(WattB + (((wv * 16 + ks) * 64 + lane) << 3));
        acc1 = mfma16(__builtin_bit_cast(bf16x8, av), __builtin_bit_cast(bf16x8, bw), acc1);
      }
      if (lane < 16){
        hcp[0][wv * 16 + lane] = acc1[0];   // D row 0 = v0
        hcp[1][wv * 16 + lane] = acc1[1];   // D row 1 = v1
      }
    }

    // P4: gate dots (MFMA, all A rows = h_j); wave: j=wv>>3, 8 nt tiles as 4 pairs.
    // Tile-pair structure keeps only 2 accumulators (8 AGPR) + ~12 load regs live -> no spill.
    {
      const int j = wv >> 3, ntb = (wv & 7) * 8;
      const u16* wb = WhhB + j * 262144;
      #pragma unroll 1
      for (int tp = 0; tp < 4; ++tp){
        const int nt0 = ntb + 2 * tp, nt1 = nt0 + 1;
        f32x4 acc0 = (f32x4){0.f, 0.f, 0.f, 0.f};
        f32x4 acc1 = (f32x4){0.f, 0.f, 0.f, 0.f};
        #pragma unroll
        for (int ks = 0; ks < 8; ++ks){
          const uint4 av = *(const uint4*)&hcB[j][ks * 32 + q * 8];
          const bf16x8 a = __builtin_bit_cast(bf16x8, av);
          const uint4 b0 = *(const uint4*)(wb + (((nt0 * 8 + ks) * 64 + lane) << 3));
          const uint4 b1 = *(const uint4*)(wb + (((nt1 * 8 + ks) * 64 + lane) << 3));
          acc0 = mfma16(a, __builtin_bit_cast(bf16x8, b0), acc0);
          acc1 = mfma16(a, __builtin_bit_cast(bf16x8, b1), acc1);
        }
        if (lane < 16){
          preS[j][nt0 * 16 + lane] = acc0[0];  // all D rows equal
          preS[j][nt1 * 16 + lane] = acc1[0];
        }
      }
    }
    __syncthreads();  // S1: hcp, preS ready

    // P2: scores[s] = sum_h w3[h]*tanh(encT[s][h] + hcp[s&1][h]); wave wv: s = wv*4+r
    {
      float hqA[4], hqB[4];
      #pragma unroll
      for (int qq = 0; qq < 4; ++qq){
        hqA[qq] = hcp[0][lane + 64 * qq];
        hqB[qq] = hcp[1][lane + 64 * qq];
      }
      #pragma unroll
      for (int r = 0; r < 4; ++r){
        const int s = wv * 4 + r;
        const float h0v = (r & 1) ? hqB[0] : hqA[0];
        const float h1v = (r & 1) ? hqB[1] : hqA[1];
        const float h2v = (r & 1) ? hqB[2] : hqA[2];
        const float h3v = (r & 1) ? hqB[3] : hqA[3];
        float psum = w3q0 * tanh_fast(bf2f(encT[s * 256 + lane])       + h0v)
                   + w3q1 * tanh_fast(bf2f(encT[s * 256 + lane + 64])  + h1v)
                   + w3q2 * tanh_fast(bf2f(encT[s * 256 + lane + 128]) + h2v)
                   + w3q3 * tanh_fast(bf2f(encT[s * 256 + lane + 192]) + h3v);
        psum = wave_sum(psum);
        if (lane == 0) scores[s] = psum;
      }
    }
    __syncthreads();  // S2: scores ready

    // softmax (wave 0)
    if (tid < 64){
      const float v = scores[tid];
      float mx = v;
      #pragma unroll
      for (int o = 32; o > 0; o >>= 1) mx = fmaxf(mx, __shfl_xor(mx, o, 64));
      const float e = __builtin_amdgcn_exp2f((v - mx) * 1.44269504089f);
      float sm = e;
      #pragma unroll
      for (int o = 32; o > 0; o >>= 1) sm += __shfl_xor(sm, o, 64);
      const float a = e / sm;
      attw[tid] = a;
      attw_acc[tid] += a;
    }
    __syncthreads();  // S3: attw ready

    // P3: context partials from LDS bf16 enc; thread = (m3, sh2), 32 s each
    {
      float ca = 0.f;
      #pragma unroll 8
      for (int si = 0; si < 32; ++si){
        const int s = sh2 * 32 + si;
        ca += attw[s] * bf2f(encLDS[s * 512 + m3]);
      }
      ctxp[sh2][m3] = ca;
    }
    __syncthreads();  // S4: ctxp ready

    if (tid < 512){
      const float c = ctxp[0][tid] + ctxp[1][tid];
      ctx[tid] = c;
      float yp = c * fe;
      yp = wave_sum(yp);
      if (lane == 0) red[wv] = yp;
    }
    __syncthreads();  // S5: red ready

    // update: LSTM cell (tid<512); preS holds raw gate dots
    if (tid < 512){
      const float ytil = (red[0] + red[1] + red[2] + red[3] +
                          red[4] + red[5] + red[6] + red[7]) +
                         yS[t] * feY + sS[t] * feS + feB;
      const float pi = preS[jj][pp]       + ytil * wv_i + gb_i;
      const float pf = preS[jj][pp + 256] + ytil * wv_f + gb_f;
      const float pg = preS[jj][pp + 512] + ytil * wv_g + gb_g;
      const float po = preS[jj][pp + 768] + ytil * wv_o + gb_o;
      const float cold = hcin[jj][256 + pp];
      const float cnew = sigm(pf) * cold + sigm(pi) * tanh_fast(pg);
      const float hnew = sigm(po) * tanh_fast(cnew);
      hcin[jj][256 + pp] = cnew;
      hcin[jj][pp]       = hnew;
      hcB[jj][pp]        = f2bf(hnew);
      hcB[jj][256 + pp]  = f2bf(cnew);
    }
  }

  __syncthreads();

  // ---- outputs ----
  if (tid < 64) out[b * 64 + tid] = attw_acc[tid] * 0.015625f;  // /64

  if (tid < 256){
    float part = hcin[0][tid]     * fcfw[tid]
               + ctx[tid]         * fcfw[256 + tid]
               + ctx[256 + tid]   * fcfw[512 + tid];
    part = wave_sum(part);
    if (lane == 0) red[wv] = part;
  }
  __syncthreads();
  if (tid == 0) out[16384 + b] = red[0] + red[1] + red[2] + red[3] + fcfb[0];
}

// ---------------- launch ----------------
extern "C" void kernel_launch(void* const* d_in, const int* in_sizes, int n_in,
                              void* d_out, int out_size, void* d_ws, size_t ws_size,
                              hipStream_t stream)
{
  const float* enc  = (const float*)d_in[0];
  const float* yh   = (const float*)d_in[1];
  const float* sp   = (const float*)d_in[2];
  const float* h0   = (const float*)d_in[3];
  const float* c0   = (const float*)d_in[4];
  const float* w1   = (const float*)d_in[5];
  const float* b1   = (const float*)d_in[6];
  const float* w2   = (const float*)d_in[7];
  const float* b2   = (const float*)d_in[8];
  const float* w3   = (const float*)d_in[9];
  const float* wihf = (const float*)d_in[11];
  const float* whhf = (const float*)d_in[12];
  const float* bihf = (const float*)d_in[13];
  const float* bhhf = (const float*)d_in[14];
  const float* wihb = (const float*)d_in[15];
  const float* whhb = (const float*)d_in[16];
  const float* bihb = (const float*)d_in[17];
  const float* bhhb = (const float*)d_in[18];
  const float* fcw1 = (const float*)d_in[19];
  const float* fcb1 = (const float*)d_in[20];
  const float* fcw2 = (const float*)d_in[21];
  const float* fcb2 = (const float*)d_in[22];
  const float* fcfw = (const float*)d_in[23];
  const float* fcfb = (const float*)d_in[24];

  char* ws = (char*)d_ws;
  u16*   WattB = (u16*)(ws);
  u16*   WencB = (u16*)(ws + 262144);
  u16*   WhhB  = (u16*)(ws + 524288);
  float* beff  = (float*)(ws + 1572864);
  float* gbias = (float*)(ws + 1573888);
  float* fcE   = (float*)(ws + 1582080);
  float* out   = (float*)d_out;

  prep_attn<<<dim3(256),  dim3(256), 0, stream>>>(w1, b1, w2, b2, WattB, WencB, beff);
  prep_whh <<<dim3(2048), dim3(256), 0, stream>>>(whhf, whhb, bihf, bhhf, bihb, bhhb, WhhB, gbias);
  prep_fc  <<<dim3(1),    dim3(256), 0, stream>>>(fcw1, fcb1, fcw2, fcb2, fcE);
  decoder_main<<<dim3(256), dim3(1024), 0, stream>>>(
      enc, yh, sp, h0, c0, w3, wihf, wihb, fcfw, fcfb,
      WattB, WencB, WhhB, beff, gbias, fcE, out);
}